// Round 1
// baseline (365.785 us; speedup 1.0000x reference)
//
#include <hip/hip_runtime.h>
#include <hip/hip_bf16.h>
#include <cfloat>
#include <climits>

#define BS   32
#define NQ   300
#define NC   8192
#define NOBJ 64
#define NROW (BS * NQ)   // 9600

// ---------------------------------------------------------------------------
// Kernel 1: compact nonzero labels per batch (targets) -> tgt_cls, sizes
// ---------------------------------------------------------------------------
__global__ void compact_kernel(const int* __restrict__ labels,
                               int* __restrict__ tgt_cls,
                               int* __restrict__ sizes) {
    int b = threadIdx.x;
    if (b >= BS) return;
    int cnt = 0;
    for (int k = 0; k < NOBJ; ++k) {
        int lab = labels[b * NOBJ + k];
        if (lab != 0) {
            tgt_cls[b * NOBJ + cnt] = lab;
            ++cnt;
        }
    }
    sizes[b] = cnt;
}

// ---------------------------------------------------------------------------
// Kernel 2: logZ per row (online softmax denominator), one wave per row.
// ---------------------------------------------------------------------------
__global__ __launch_bounds__(256) void logz_kernel(const float* __restrict__ x,
                                                   float* __restrict__ logZ) {
    int wave = threadIdx.x >> 6;
    int lane = threadIdx.x & 63;
    int row  = blockIdx.x * 4 + wave;
    if (row >= NROW) return;
    const float4* p = (const float4*)(x + (size_t)row * NC);
    float m = -INFINITY, s = 0.f;
    #pragma unroll 4
    for (int k = 0; k < NC / 4 / 64; ++k) {   // 32 float4 per lane
        float4 v = p[lane + k * 64];
        #pragma unroll
        for (int e = 0; e < 4; ++e) {
            float xv = (&v.x)[e];
            if (xv <= m) {
                s += __expf(xv - m);
            } else {
                s = s * __expf(m - xv) + 1.f;
                m = xv;
            }
        }
    }
    // cross-lane (m, s) combine
    for (int off = 32; off; off >>= 1) {
        float om = __shfl_xor(m, off);
        float os = __shfl_xor(s, off);
        float nm = fmaxf(m, om);
        s = s * __expf(m - nm) + os * __expf(om - nm);
        m = nm;
    }
    if (lane == 0) logZ[row] = m + logf(s);
}

// ---------------------------------------------------------------------------
// Kernel 3: costT[b][t][q] = -exp(x[b,q,cls] - logZ[b,q])   (transposed cost)
// ---------------------------------------------------------------------------
__global__ void cost_kernel(const float* __restrict__ x,
                            const float* __restrict__ logZ,
                            const int* __restrict__ tgt_cls,
                            const int* __restrict__ sizes,
                            float* __restrict__ costT) {
    int b = blockIdx.x >> 6;   // BS*NOBJ blocks
    int t = blockIdx.x & 63;
    if (t >= sizes[b]) return;
    int cls = tgt_cls[b * NOBJ + t];
    for (int q = threadIdx.x; q < NQ; q += blockDim.x) {
        float xv = x[((size_t)b * NQ + q) * NC + cls];
        float lz = logZ[b * NQ + q];
        costT[((size_t)b * NOBJ + t) * NQ + q] = -__expf(xv - lz);
    }
}

// ---------------------------------------------------------------------------
// Kernel 4: Jonker-Volgenant rectangular assignment, one wave per batch.
// Solves the transposed problem (n = sizes[b] rows <= 64, m = 300 cols),
// faithful to the numpy reference (f64, first-index argmin tie-break).
// Writes tgtq[b][q] = assigned target index (0 if unmatched).
// ---------------------------------------------------------------------------
__global__ __launch_bounds__(64) void hungarian_kernel(const float* __restrict__ costT,
                                                       const int* __restrict__ sizes,
                                                       int* __restrict__ tgtq) {
    const int m = NQ;          // 300 columns (queries)
    int b    = blockIdx.x;
    int lane = threadIdx.x;
    int n    = sizes[b];

    __shared__ double u[NOBJ + 1];
    __shared__ double v[NQ + 1];
    __shared__ double minv[NQ + 1];
    __shared__ int    p[NQ + 1];
    __shared__ int    way[NQ + 1];
    __shared__ unsigned char used[NQ + 1];

    for (int j = lane; j <= m; j += 64) { v[j] = 0.0; p[j] = 0; way[j] = 0; }
    for (int i = lane; i <= NOBJ; i += 64) u[i] = 0.0;
    __syncthreads();

    for (int i = 1; i <= n; ++i) {
        for (int j = lane; j <= m; j += 64) { minv[j] = INFINITY; used[j] = 0; }
        if (lane == 0) p[0] = i;
        __syncthreads();

        int j0 = 0;
        while (true) {
            if (lane == 0) used[j0] = 1;
            __syncthreads();
            int i0 = p[j0];                       // uniform
            double ui0 = u[i0];
            const float* crow = costT + ((size_t)b * NOBJ + (i0 - 1)) * NQ;

            double bestv = INFINITY;
            int    bestj = INT_MAX;
            for (int j = 1 + lane; j <= m; j += 64) {
                if (!used[j]) {
                    double cur = (double)crow[j - 1] - ui0 - v[j];
                    double mv  = minv[j];
                    if (cur < mv) { mv = cur; minv[j] = cur; way[j] = j0; }
                    if (mv < bestv || (mv == bestv && j < bestj)) { bestv = mv; bestj = j; }
                }
            }
            // wave argmin (value, first-index tie-break)
            for (int off = 32; off; off >>= 1) {
                double ov = __shfl_xor(bestv, off);
                int    oj = __shfl_xor(bestj, off);
                if (ov < bestv || (ov == bestv && oj < bestj)) { bestv = ov; bestj = oj; }
            }
            int    j1    = bestj;
            double delta = bestv;
            __syncthreads();
            for (int j = lane; j <= m; j += 64) {
                if (used[j]) { u[p[j]] += delta; v[j] -= delta; }
                else         { minv[j] -= delta; }
            }
            __syncthreads();
            j0 = j1;
            if (p[j0] == 0) break;
        }
        // augment along the alternating path (serial, lane 0)
        if (lane == 0) {
            int jj = j0;
            while (jj) { int jn = way[jj]; p[jj] = p[jn]; jj = jn; }
        }
        __syncthreads();
    }

    for (int q = lane; q < m; q += 64) {
        int r = p[q + 1];
        tgtq[b * NQ + q] = (r > 0) ? (r - 1) : 0;
    }
}

// ---------------------------------------------------------------------------
// Kernel 5: loss = -(1/9600) * sum_i (x[i, tgt[i]] - logZ[i]), f64 accumulate
// ---------------------------------------------------------------------------
__global__ __launch_bounds__(256) void loss_kernel(const float* __restrict__ x,
                                                   const float* __restrict__ logZ,
                                                   const int* __restrict__ tgtq,
                                                   float* __restrict__ out) {
    __shared__ double sh[256];
    double acc = 0.0;
    for (int i = threadIdx.x; i < NROW; i += 256) {
        int   tgt = tgtq[i];
        float xv  = x[(size_t)i * NC + tgt];
        acc += (double)(xv - logZ[i]);
    }
    sh[threadIdx.x] = acc;
    __syncthreads();
    for (int off = 128; off; off >>= 1) {
        if (threadIdx.x < off) sh[threadIdx.x] += sh[threadIdx.x + off];
        __syncthreads();
    }
    if (threadIdx.x == 0) out[0] = (float)(-sh[0] / (double)NROW);
}

// ---------------------------------------------------------------------------
extern "C" void kernel_launch(void* const* d_in, const int* in_sizes, int n_in,
                              void* d_out, int out_size, void* d_ws, size_t ws_size,
                              hipStream_t stream) {
    const float* outputs = (const float*)d_in[0];
    const int*   labels  = (const int*)d_in[1];
    float*       out     = (float*)d_out;

    char* ws = (char*)d_ws;
    size_t off = 0;
    float* logZ    = (float*)(ws + off); off += (size_t)NROW * sizeof(float);          // 38400
    int*   tgt_cls = (int*)  (ws + off); off += (size_t)BS * NOBJ * sizeof(int);        // 8192
    int*   sizes   = (int*)  (ws + off); off += 128;                                    // 32 ints + pad
    float* costT   = (float*)(ws + off); off += (size_t)BS * NOBJ * NQ * sizeof(float); // 2.46 MB
    int*   tgtq    = (int*)  (ws + off); off += (size_t)NROW * sizeof(int);             // 38400

    compact_kernel  <<<1, 64, 0, stream>>>(labels, tgt_cls, sizes);
    logz_kernel     <<<(NROW + 3) / 4, 256, 0, stream>>>(outputs, logZ);
    cost_kernel     <<<BS * NOBJ, 256, 0, stream>>>(outputs, logZ, tgt_cls, sizes, costT);
    hungarian_kernel<<<BS, 64, 0, stream>>>(costT, sizes, tgtq);
    loss_kernel     <<<1, 256, 0, stream>>>(outputs, logZ, tgtq, out);
}

// Round 2
// 188.656 us; speedup vs baseline: 1.9389x; 1.9389x over previous
//
#include <hip/hip_runtime.h>
#include <hip/hip_bf16.h>
#include <cfloat>
#include <climits>

#define BS   32
#define NQ   300
#define NC   8192
#define NOBJ 64
#define NROW (BS * NQ)   // 9600
#define CPL  5           // cols per lane: lanes 0..59 own 5 contiguous cols (60*5=300)

// ---------------------------------------------------------------------------
// Kernel 1: compact nonzero labels per batch (targets) -> tgt_cls, sizes
// ---------------------------------------------------------------------------
__global__ void compact_kernel(const int* __restrict__ labels,
                               int* __restrict__ tgt_cls,
                               int* __restrict__ sizes) {
    int b = threadIdx.x;
    if (b >= BS) return;
    int cnt = 0;
    for (int k = 0; k < NOBJ; ++k) {
        int lab = labels[b * NOBJ + k];
        if (lab != 0) {
            tgt_cls[b * NOBJ + cnt] = lab;
            ++cnt;
        }
    }
    sizes[b] = cnt;
}

// ---------------------------------------------------------------------------
// Kernel 2: logZ per row (online softmax denominator), one wave per row.
// ---------------------------------------------------------------------------
__global__ __launch_bounds__(256) void logz_kernel(const float* __restrict__ x,
                                                   float* __restrict__ logZ) {
    int wave = threadIdx.x >> 6;
    int lane = threadIdx.x & 63;
    int row  = blockIdx.x * 4 + wave;
    if (row >= NROW) return;
    const float4* p = (const float4*)(x + (size_t)row * NC);
    float m = -INFINITY, s = 0.f;
    #pragma unroll 4
    for (int k = 0; k < NC / 4 / 64; ++k) {   // 32 float4 per lane
        float4 v = p[lane + k * 64];
        #pragma unroll
        for (int e = 0; e < 4; ++e) {
            float xv = (&v.x)[e];
            if (xv <= m) {
                s += __expf(xv - m);
            } else {
                s = s * __expf(m - xv) + 1.f;
                m = xv;
            }
        }
    }
    for (int off = 32; off; off >>= 1) {
        float om = __shfl_xor(m, off);
        float os = __shfl_xor(s, off);
        float nm = fmaxf(m, om);
        s = s * __expf(m - nm) + os * __expf(om - nm);
        m = nm;
    }
    if (lane == 0) logZ[row] = m + logf(s);
}

// ---------------------------------------------------------------------------
// Kernel 3: costT[b][t][q] = -exp(x[b,q,cls] - logZ[b,q])   (transposed cost)
// ---------------------------------------------------------------------------
__global__ void cost_kernel(const float* __restrict__ x,
                            const float* __restrict__ logZ,
                            const int* __restrict__ tgt_cls,
                            const int* __restrict__ sizes,
                            float* __restrict__ costT) {
    int b = blockIdx.x >> 6;   // BS*NOBJ blocks
    int t = blockIdx.x & 63;
    if (t >= sizes[b]) return;
    int cls = tgt_cls[b * NOBJ + t];
    for (int q = threadIdx.x; q < NQ; q += blockDim.x) {
        float xv = x[((size_t)b * NQ + q) * NC + cls];
        float lz = logZ[b * NQ + q];
        costT[((size_t)b * NOBJ + t) * NQ + q] = -__expf(xv - lz);
    }
}

// ---------------------------------------------------------------------------
// Kernel 4: Jonker-Volgenant rectangular assignment, one wave per batch.
// Cost slice staged in LDS; minv/v register-resident (contiguous 5 cols/lane);
// f64 arithmetic in the reference's exact order; first-index argmin tie-break
// via lowest-lane ballot (contiguous ownership => lowest lane == lowest j).
// ---------------------------------------------------------------------------
__global__ __launch_bounds__(64) void hungarian_kernel(const float* __restrict__ costT,
                                                       const int* __restrict__ sizes,
                                                       int* __restrict__ tgtq) {
    int b    = blockIdx.x;
    int lane = threadIdx.x;
    int n    = sizes[b];

    __shared__ float  cst[NOBJ * NQ];   // 76.8 KB
    __shared__ double u[NOBJ + 1];
    __shared__ int    p[NQ + 1];
    __shared__ int    way[NQ + 1];

    {   // stage cost slice: 4800 float4, 75 per lane, coalesced
        const float4* src = (const float4*)(costT + (size_t)b * NOBJ * NQ);
        float4* dst = (float4*)cst;
        #pragma unroll
        for (int t = 0; t < NOBJ * NQ / 4 / 64; ++t)
            dst[lane + t * 64] = src[lane + t * 64];
    }
    for (int j = lane; j <= NQ; j += 64) { p[j] = 0; way[j] = 0; }
    if (lane <= NOBJ - 1) u[lane] = 0.0;
    if (lane == 0) u[NOBJ] = 0.0;
    __syncthreads();

    const int  jbase    = lane * CPL + 1;
    const bool haveCols = (lane < 60);
    double v_r[CPL], minv_r[CPL];
    #pragma unroll
    for (int k = 0; k < CPL; ++k) v_r[k] = 0.0;

    for (int i = 1; i <= n; ++i) {
        #pragma unroll
        for (int k = 0; k < CPL; ++k) minv_r[k] = INFINITY;
        int used = 0;
        int j0 = 0, i0 = i;                // p[0] = i held implicitly
        while (true) {
            if (j0 > 0 && (unsigned)(j0 - 1) / CPL == (unsigned)lane)
                used |= 1 << ((j0 - 1) % CPL);
            double ui0 = u[i0];
            const float* crow = cst + (i0 - 1) * NQ;

            double lv = INFINITY;
            int    lj = INT_MAX;
            if (haveCols) {
                #pragma unroll
                for (int k = 0; k < CPL; ++k) {
                    if (!((used >> k) & 1)) {
                        double cur = (double)crow[jbase - 1 + k] - ui0 - v_r[k];
                        if (cur < minv_r[k]) { minv_r[k] = cur; way[jbase + k] = j0; }
                        double mv = minv_r[k];
                        if (mv < lv) { lv = mv; lj = jbase + k; }   // k asc -> first j
                    }
                }
            }
            // global min value (exact), then first-lane (== first-j) recovery
            double gv = lv;
            #pragma unroll
            for (int off = 32; off; off >>= 1)
                gv = fmin(gv, __shfl_xor(gv, off));
            unsigned long long msk = __ballot(lv == gv);
            int owner = __ffsll(msk) - 1;
            int j1    = __shfl(lj, owner);
            double delta = gv;

            // price updates (reference order: u[p[used]] += d; v[used] -= d; minv[free] -= d)
            if (lane == 0) u[i] += delta;              // virtual column j0=0 (p[0]=i)
            if (haveCols) {
                #pragma unroll
                for (int k = 0; k < CPL; ++k) {
                    if ((used >> k) & 1) { u[p[jbase + k]] += delta; v_r[k] -= delta; }
                    else                   minv_r[k] -= delta;
                }
            }
            i0 = p[j1];          // p stable within a row's search
            __syncthreads();     // drain u writes before next u[i0] read
            j0 = j1;
            if (i0 == 0) break;
        }
        // augment alternating path (serial, lane 0); way entries on the path
        // are all from this row (minv reinit'd to inf each row)
        if (lane == 0) {
            int jj = j0;
            while (jj) {
                int jn = way[jj];
                p[jj] = jn ? p[jn] : i;   // p[0] == i
                jj = jn;
            }
        }
        __syncthreads();
    }

    for (int q = lane; q < NQ; q += 64) {
        int r = p[q + 1];
        tgtq[b * NQ + q] = (r > 0) ? (r - 1) : 0;
    }
}

// ---------------------------------------------------------------------------
// Kernel 5a/5b: loss = -(1/9600) * sum_i (x[i, tgt[i]] - logZ[i])
// 40-block partial (each thread <= 1 row) + single-block final reduce.
// ---------------------------------------------------------------------------
#define LBLK 40
__global__ __launch_bounds__(256) void loss_partial_kernel(const float* __restrict__ x,
                                                           const float* __restrict__ logZ,
                                                           const int* __restrict__ tgtq,
                                                           double* __restrict__ partial) {
    __shared__ double sh[256];
    int i = blockIdx.x * 256 + threadIdx.x;   // 40*256 = 10240 >= 9600
    double acc = 0.0;
    if (i < NROW) {
        int   tgt = tgtq[i];
        float xv  = x[(size_t)i * NC + tgt];
        acc = (double)(xv - logZ[i]);
    }
    sh[threadIdx.x] = acc;
    __syncthreads();
    for (int off = 128; off; off >>= 1) {
        if (threadIdx.x < off) sh[threadIdx.x] += sh[threadIdx.x + off];
        __syncthreads();
    }
    if (threadIdx.x == 0) partial[blockIdx.x] = sh[0];
}

__global__ __launch_bounds__(64) void loss_final_kernel(const double* __restrict__ partial,
                                                        float* __restrict__ out) {
    int lane = threadIdx.x;
    double acc = (lane < LBLK) ? partial[lane] : 0.0;
    for (int off = 32; off; off >>= 1)
        acc += __shfl_xor(acc, off);
    if (lane == 0) out[0] = (float)(-acc / (double)NROW);
}

// ---------------------------------------------------------------------------
extern "C" void kernel_launch(void* const* d_in, const int* in_sizes, int n_in,
                              void* d_out, int out_size, void* d_ws, size_t ws_size,
                              hipStream_t stream) {
    const float* outputs = (const float*)d_in[0];
    const int*   labels  = (const int*)d_in[1];
    float*       out     = (float*)d_out;

    char* ws = (char*)d_ws;
    size_t off = 0;
    float*  logZ    = (float*)(ws + off);  off += (size_t)NROW * sizeof(float);
    int*    tgt_cls = (int*)  (ws + off);  off += (size_t)BS * NOBJ * sizeof(int);
    int*    sizes   = (int*)  (ws + off);  off += 128;
    float*  costT   = (float*)(ws + off);  off += (size_t)BS * NOBJ * NQ * sizeof(float);
    int*    tgtq    = (int*)  (ws + off);  off += (size_t)NROW * sizeof(int);
    double* partial = (double*)(ws + off); off += (size_t)LBLK * sizeof(double);

    compact_kernel     <<<1, 64, 0, stream>>>(labels, tgt_cls, sizes);
    logz_kernel        <<<(NROW + 3) / 4, 256, 0, stream>>>(outputs, logZ);
    cost_kernel        <<<BS * NOBJ, 256, 0, stream>>>(outputs, logZ, tgt_cls, sizes, costT);
    hungarian_kernel   <<<BS, 64, 0, stream>>>(costT, sizes, tgtq);
    loss_partial_kernel<<<LBLK, 256, 0, stream>>>(outputs, logZ, tgtq, partial);
    loss_final_kernel  <<<1, 64, 0, stream>>>(partial, out);
}

// Round 3
// 157.980 us; speedup vs baseline: 2.3154x; 1.1942x over previous
//
#include <hip/hip_runtime.h>
#include <hip/hip_bf16.h>
#include <cfloat>
#include <climits>

#define BS   32
#define NQ   300
#define NC   8192
#define NOBJ 64
#define NROW (BS * NQ)   // 9600
#define CPL  5           // cols per lane: lanes 0..59 own 5 contiguous cols
#define LPAD 65          // padded LDS row stride (words) for [j][t] cost tile

// ---------------------------------------------------------------------------
// helpers: f64 broadcast from a lane (2x v_readlane), DPP f64 min step
// ---------------------------------------------------------------------------
__device__ __forceinline__ double bcast_f64(double v, int lane) {
    union { double d; int i[2]; } c, r;
    c.d = v;
    r.i[0] = __builtin_amdgcn_readlane(c.i[0], lane);
    r.i[1] = __builtin_amdgcn_readlane(c.i[1], lane);
    return r.d;
}

template <int CTRL>
__device__ __forceinline__ double dpp_min_step(double x) {
    union { double d; int i[2]; } c, r;
    c.d = x;
    r.i[0] = __builtin_amdgcn_update_dpp(c.i[0], c.i[0], CTRL, 0xF, 0xF, false);
    r.i[1] = __builtin_amdgcn_update_dpp(c.i[1], c.i[1], CTRL, 0xF, 0xF, false);
    return fmin(x, r.d);
}

// full-wave64 min: result valid in lane 63 (canonical gfx9 sequence)
__device__ __forceinline__ double wave_min_f64(double x) {
    x = dpp_min_step<0x111>(x);  // row_shr:1
    x = dpp_min_step<0x112>(x);  // row_shr:2
    x = dpp_min_step<0x114>(x);  // row_shr:4
    x = dpp_min_step<0x118>(x);  // row_shr:8
    x = dpp_min_step<0x142>(x);  // row_bcast:15
    x = dpp_min_step<0x143>(x);  // row_bcast:31
    return x;
}

// ---------------------------------------------------------------------------
// Kernel 1: compact nonzero labels per batch -> tgt_cls (zero-padded), sizes
// ---------------------------------------------------------------------------
__global__ void compact_kernel(const int* __restrict__ labels,
                               int* __restrict__ tgt_cls,
                               int* __restrict__ sizes) {
    int b = threadIdx.x;
    if (b >= BS) return;
    int cnt = 0;
    for (int k = 0; k < NOBJ; ++k) {
        int lab = labels[b * NOBJ + k];
        if (lab != 0) tgt_cls[b * NOBJ + cnt++] = lab;
    }
    sizes[b] = cnt;
    for (int k = cnt; k < NOBJ; ++k) tgt_cls[b * NOBJ + k] = 0;  // defensive
}

// ---------------------------------------------------------------------------
// Kernel 2 (fused): logZ per row + cost row costQ[row][t] = -exp(x - logZ)
// One wave per row; cost write is one coalesced 256B store.
// ---------------------------------------------------------------------------
__global__ __launch_bounds__(256) void logz_cost_kernel(const float* __restrict__ x,
                                                        const int* __restrict__ tgt_cls,
                                                        const int* __restrict__ sizes,
                                                        float* __restrict__ logZ,
                                                        float* __restrict__ costQ) {
    int wave = threadIdx.x >> 6;
    int lane = threadIdx.x & 63;
    int row  = blockIdx.x * 4 + wave;
    if (row >= NROW) return;
    const float4* p = (const float4*)(x + (size_t)row * NC);
    float m = -INFINITY, s = 0.f;
    #pragma unroll 4
    for (int k = 0; k < NC / 4 / 64; ++k) {   // 32 float4 per lane
        float4 v = p[lane + k * 64];
        #pragma unroll
        for (int e = 0; e < 4; ++e) {
            float xv = (&v.x)[e];
            if (xv <= m) {
                s += __expf(xv - m);
            } else {
                s = s * __expf(m - xv) + 1.f;
                m = xv;
            }
        }
    }
    for (int off = 32; off; off >>= 1) {
        float om = __shfl_xor(m, off);
        float os = __shfl_xor(s, off);
        float nm = fmaxf(m, om);
        s = s * __expf(m - nm) + os * __expf(om - nm);
        m = nm;
    }
    float lz = m + logf(s);                    // all lanes hold it
    if (lane == 0) logZ[row] = lz;

    int b  = row / NQ;
    int nb = sizes[b];
    float c = 0.f;
    if (lane < nb) {
        int   cls = tgt_cls[b * NOBJ + lane];
        float xv  = x[(size_t)row * NC + cls]; // row is L1/L2-hot
        c = -__expf(xv - lz);
    }
    costQ[(size_t)row * NOBJ + lane] = c;      // coalesced
}

// ---------------------------------------------------------------------------
// Kernel 3: Jonker-Volgenant, one wave per batch, all state in registers.
//   cost tile in LDS [j][t] (pad-65: staging & reads 2 lanes/bank = free)
//   u distributed by row (1/lane), v/minv/p/way distributed by column (5/lane)
//   DPP f64 min-reduce + readlane broadcasts; register augment walk.
// f64 ops in the reference's exact order; first-index tie-break preserved.
// ---------------------------------------------------------------------------
__global__ __launch_bounds__(64) void hungarian_kernel(const float* __restrict__ costQ,
                                                       const int* __restrict__ sizes,
                                                       int* __restrict__ tgtq) {
    int b    = blockIdx.x;
    int lane = threadIdx.x;
    int n    = sizes[b];

    __shared__ float cst[NQ * LPAD];   // 300*65*4 = 78 KB
    {   // stage costQ -> LDS with transpose-pad; coalesced float4 reads
        const float4* src = (const float4*)(costQ + (size_t)b * NQ * NOBJ);
        #pragma unroll
        for (int t = 0; t < NQ * NOBJ / 4 / 64; ++t) {   // 75
            float4 v = src[lane + t * 64];
            int e  = 4 * (lane + t * 64);
            int j  = e >> 6;        // query index
            int t0 = e & 63;        // target index (multiple of 4)
            float* d = &cst[j * LPAD + t0];
            d[0] = v.x; d[1] = v.y; d[2] = v.z; d[3] = v.w;
        }
    }
    __syncthreads();

    const int  jbase    = lane * CPL + 1;
    const bool haveCols = (lane < 60);
    double v_r[CPL], minv_r[CPL];
    int    p_r[CPL], way_r[CPL];
    double u_val = 0.0;                 // u for row (lane+1)
    #pragma unroll
    for (int k = 0; k < CPL; ++k) { v_r[k] = 0.0; p_r[k] = 0; way_r[k] = 0; }

    for (int i = 1; i <= n; ++i) {
        #pragma unroll
        for (int k = 0; k < CPL; ++k) minv_r[k] = INFINITY;
        int  usedbits = 0;
        bool inTree   = (lane == i - 1);   // virtual col 0: p[0]=i
        int  i0 = i, j0 = 0, jfin;

        while (true) {
            double ui0   = bcast_f64(u_val, i0 - 1);
            int    cbase = i0 - 1;
            double lv = INFINITY;
            int    lj = INT_MAX;
            if (haveCols) {
                #pragma unroll
                for (int k = 0; k < CPL; ++k) {
                    if (!((usedbits >> k) & 1)) {
                        double cur = (double)cst[(jbase - 1 + k) * LPAD + cbase] - ui0 - v_r[k];
                        if (cur < minv_r[k]) { minv_r[k] = cur; way_r[k] = j0; }
                        double mv = minv_r[k];
                        if (mv < lv) { lv = mv; lj = jbase + k; }  // k asc -> first j
                    }
                }
            }
            double delta = bcast_f64(wave_min_f64(lv), 63);
            unsigned long long msk = __ballot(lv == delta);
            int ownerLane = (int)__ffsll((unsigned long long)msk) - 1;
            int j1        = __builtin_amdgcn_readlane(lj, ownerLane);

            // price updates (reference order; exact same f64 sums)
            if (inTree) u_val += delta;
            if (haveCols) {
                #pragma unroll
                for (int k = 0; k < CPL; ++k) {
                    if ((usedbits >> k) & 1) v_r[k]    -= delta;
                    else                     minv_r[k] -= delta;
                }
            }

            int k1u = (j1 - 1) % CPL;          // uniform
            int ow1 = (j1 - 1) / CPL;          // == ownerLane
            int pv  = p_r[0];
            pv = (k1u == 1) ? p_r[1] : pv;
            pv = (k1u == 2) ? p_r[2] : pv;
            pv = (k1u == 3) ? p_r[3] : pv;
            pv = (k1u == 4) ? p_r[4] : pv;
            int i0n = __builtin_amdgcn_readlane(pv, ow1);

            if (lane == ow1) usedbits |= (1 << k1u);   // used at next iter top
            if (i0n == 0) { jfin = j1; break; }
            if (lane == i0n - 1) inTree = true;
            i0 = i0n; j0 = j1;
        }

        // augment alternating path: p[jj] = p[way[jj]] (p[0] == i)
        int jj = jfin;
        while (jj) {
            int ow = (jj - 1) / CPL, kk = (jj - 1) % CPL;
            int wv = way_r[0];
            wv = (kk == 1) ? way_r[1] : wv;
            wv = (kk == 2) ? way_r[2] : wv;
            wv = (kk == 3) ? way_r[3] : wv;
            wv = (kk == 4) ? way_r[4] : wv;
            int jn = __builtin_amdgcn_readlane(wv, ow);
            int pn;
            if (jn == 0) {
                pn = i;
            } else {
                int ow2 = (jn - 1) / CPL, kk2 = (jn - 1) % CPL;
                int pv2 = p_r[0];
                pv2 = (kk2 == 1) ? p_r[1] : pv2;
                pv2 = (kk2 == 2) ? p_r[2] : pv2;
                pv2 = (kk2 == 3) ? p_r[3] : pv2;
                pv2 = (kk2 == 4) ? p_r[4] : pv2;
                pn = __builtin_amdgcn_readlane(pv2, ow2);
            }
            bool w = (lane == ow);
            p_r[0] = (w && kk == 0) ? pn : p_r[0];
            p_r[1] = (w && kk == 1) ? pn : p_r[1];
            p_r[2] = (w && kk == 2) ? pn : p_r[2];
            p_r[3] = (w && kk == 3) ? pn : p_r[3];
            p_r[4] = (w && kk == 4) ? pn : p_r[4];
            jj = jn;
        }
    }

    if (haveCols) {
        #pragma unroll
        for (int k = 0; k < CPL; ++k) {
            int pr = p_r[k];
            tgtq[b * NQ + (jbase - 1 + k)] = (pr > 0) ? pr - 1 : 0;
        }
    }
}

// ---------------------------------------------------------------------------
// Kernel 4a/4b: loss = -(1/9600) * sum_i (x[i, tgt[i]] - logZ[i])
// ---------------------------------------------------------------------------
#define LBLK 40
__global__ __launch_bounds__(256) void loss_partial_kernel(const float* __restrict__ x,
                                                           const float* __restrict__ logZ,
                                                           const int* __restrict__ tgtq,
                                                           double* __restrict__ partial) {
    __shared__ double sh[256];
    int i = blockIdx.x * 256 + threadIdx.x;   // 40*256 = 10240 >= 9600
    double acc = 0.0;
    if (i < NROW) {
        int   tgt = tgtq[i];
        float xv  = x[(size_t)i * NC + tgt];
        acc = (double)(xv - logZ[i]);
    }
    sh[threadIdx.x] = acc;
    __syncthreads();
    for (int off = 128; off; off >>= 1) {
        if (threadIdx.x < off) sh[threadIdx.x] += sh[threadIdx.x + off];
        __syncthreads();
    }
    if (threadIdx.x == 0) partial[blockIdx.x] = sh[0];
}

__global__ __launch_bounds__(64) void loss_final_kernel(const double* __restrict__ partial,
                                                        float* __restrict__ out) {
    int lane = threadIdx.x;
    double acc = (lane < LBLK) ? partial[lane] : 0.0;
    for (int off = 32; off; off >>= 1)
        acc += __shfl_xor(acc, off);
    if (lane == 0) out[0] = (float)(-acc / (double)NROW);
}

// ---------------------------------------------------------------------------
extern "C" void kernel_launch(void* const* d_in, const int* in_sizes, int n_in,
                              void* d_out, int out_size, void* d_ws, size_t ws_size,
                              hipStream_t stream) {
    const float* outputs = (const float*)d_in[0];
    const int*   labels  = (const int*)d_in[1];
    float*       out     = (float*)d_out;

    char* ws = (char*)d_ws;
    size_t off = 0;
    float*  logZ    = (float*)(ws + off);  off += (size_t)NROW * sizeof(float);
    int*    tgt_cls = (int*)  (ws + off);  off += (size_t)BS * NOBJ * sizeof(int);
    int*    sizes   = (int*)  (ws + off);  off += 128;
    float*  costQ   = (float*)(ws + off);  off += (size_t)NROW * NOBJ * sizeof(float);
    int*    tgtq    = (int*)  (ws + off);  off += (size_t)NROW * sizeof(int);
    double* partial = (double*)(ws + off); off += (size_t)LBLK * sizeof(double);

    compact_kernel     <<<1, 64, 0, stream>>>(labels, tgt_cls, sizes);
    logz_cost_kernel   <<<(NROW + 3) / 4, 256, 0, stream>>>(outputs, tgt_cls, sizes, logZ, costQ);
    hungarian_kernel   <<<BS, 64, 0, stream>>>(costQ, sizes, tgtq);
    loss_partial_kernel<<<LBLK, 256, 0, stream>>>(outputs, logZ, tgtq, partial);
    loss_final_kernel  <<<1, 64, 0, stream>>>(partial, out);
}